// Round 4
// baseline (131.914 us; speedup 1.0000x reference)
//
#include <hip/hip_runtime.h>

#define B_   32
#define ICN  1152
#define OCN  10
#define IDN  8
#define ODN  16
#define ODH  8                  // od half width (split across 2 lanes)
#define NIT  5
#define EPS  1e-20f
#define OUTN (B_ * OCN * ODN)   // 5120
#define BGRP 11                 // ceil(32 b / 3 groups per wave)
#define NWAVE (BGRP * ICN)      // 12672 logical waves
#define WPB  8                  // waves per block (512 threads, 8 consecutive ic)
#define NBLK (NWAVE / WPB)      // 1584 workgroups

// Pair-swap lanes (2k,2k+1) via DPP quad_perm [1,0,3,2] = 0xB1.
__device__ __forceinline__ float dpp_swap1(float x) {
  return __int_as_float(__builtin_amdgcn_update_dpp(
      0, __float_as_int(x), 0xB1, 0xF, 0xF, true));
}

// Pin a value into a VGPR: the asm result is not rematerializable, so the
// compiler cannot demote the array back to "reload from global each use".
// R3 evidence: VGPR_Count=52 < 64 proves wr[8][8] was NOT register-resident;
// every phase re-fetched weights through L1 with vmcnt waits on the critical
// path (VALUBusy 27%, latency-bound). This forces true residency.
__device__ __forceinline__ void pin(float& x) {
  asm volatile("" : "+v"(x));
}

// ---------------------------------------------------------------------------
// R4: identical structure to R3 (8 waves/block, LDS ic-reduction, atomic
// output, no workspace) with ONE change: wr/xn pinned into registers.
//
// Per wave: 3 (b,ic) groups of 20 lanes (10 oc x 2 od-halves), lanes 60..63
// idle; groups share ic, differ in b. 5 NNMF iterations, od-pair reductions
// via DPP, alpha oc-sum via 10 in-wave shuffles. Block reduces its 8 ic in
// LDS (conflict-free layout), then 480 atomicAdds per block.
// ---------------------------------------------------------------------------
__global__ __launch_bounds__(512, 4) void caps_main(
    const float* __restrict__ xg, const float* __restrict__ wg,
    float* __restrict__ outg) {
  __shared__ float red[WPB * 512];   // 16 KB
  const int l = threadIdx.x & 63;
  const int w = threadIdx.x >> 6;
  const int wid = blockIdx.x * WPB + w;  // global wave id
  const int ic = wid % ICN;
  const int bgrp = wid / ICN;    // 0..10, uniform across the block
  const int grp = l / 20;        // 0..3 (3 = idle lanes 60..63)
  const int q = l % 20;
  const int oc = q >> 1;         // 0..9
  const int half = q & 1;        // 0,1
  const int b = bgrp * 3 + grp;
  const int bb = (b < B_) ? b : (B_ - 1);   // clamp for loads only

  // ---- weights slice -> registers (PINNED): w[ic][oc][id][half*8 .. +8) ----
  float wr[IDN][ODH];
  {
    const float* wp = wg + ((size_t)ic * OCN + oc) * (IDN * ODN) + half * ODH;
#pragma unroll
    for (int id = 0; id < IDN; ++id) {
      const float4 v0 = *(const float4*)(wp + id * ODN);
      const float4 v1 = *(const float4*)(wp + id * ODN + 4);
      wr[id][0] = v0.x; wr[id][1] = v0.y; wr[id][2] = v0.z; wr[id][3] = v0.w;
      wr[id][4] = v1.x; wr[id][5] = v1.y; wr[id][6] = v1.z; wr[id][7] = v1.w;
    }
#pragma unroll
    for (int id = 0; id < IDN; ++id)
#pragma unroll
      for (int k = 0; k < ODH; ++k) pin(wr[id][k]);
  }

  // ---- x[b,ic,:] normalized over id (PINNED) ----
  float xn[IDN];
  {
    const float* xp = xg + ((size_t)bb * ICN + ic) * IDN;
    const float4 a0 = ((const float4*)xp)[0];
    const float4 a1 = ((const float4*)xp)[1];
    xn[0] = a0.x; xn[1] = a0.y; xn[2] = a0.z; xn[3] = a0.w;
    xn[4] = a1.x; xn[5] = a1.y; xn[6] = a1.z; xn[7] = a1.w;
    const float s = ((xn[0] + xn[1]) + (xn[2] + xn[3])) +
                    ((xn[4] + xn[5]) + (xn[6] + xn[7]));
    const float r = __builtin_amdgcn_rcpf(s + EPS);
#pragma unroll
    for (int i = 0; i < IDN; ++i) { xn[i] *= r; pin(xn[i]); }
  }

  // ---- NNMF iterations (phase-batched for ILP, DPP for pair reductions) ----
  float h[ODH];
#pragma unroll
  for (int k = 0; k < ODH; ++k) h[k] = 1.0f / ODN;

  for (int it = 0; it < NIT; ++it) {
    float pd[IDN];
#pragma unroll
    for (int id = 0; id < IDN; ++id) {
      float p = 0.f;
#pragma unroll
      for (int k = 0; k < ODH; ++k) p = fmaf(h[k], wr[id][k], p);
      pd[id] = p;
    }
    float tc[IDN];
#pragma unroll
    for (int id = 0; id < IDN; ++id) {
      const float den = pd[id] + dpp_swap1(pd[id]);   // full 16-od sum
      tc[id] = xn[id] * __builtin_amdgcn_rcpf(den + EPS);
    }
    float hacc[ODH];
#pragma unroll
    for (int k = 0; k < ODH; ++k) hacc[k] = wr[0][k] * tc[0];
#pragma unroll
    for (int id = 1; id < IDN; ++id)
#pragma unroll
      for (int k = 0; k < ODH; ++k) hacc[k] = fmaf(wr[id][k], tc[id], hacc[k]);
#pragma unroll
    for (int k = 0; k < ODH; ++k) h[k] *= hacc[k];
    const float ps = ((h[0] + h[1]) + (h[2] + h[3])) +
                     ((h[4] + h[5]) + (h[6] + h[7]));
    const float hs = ps + dpp_swap1(ps);              // full 16-od sum
    const float r = __builtin_amdgcn_rcpf(hs + EPS);
#pragma unroll
    for (int k = 0; k < ODH; ++k) h[k] *= r;
  }

  // ---- alpha = sum_id (sum_od h*w) * xn, normalized over oc ----
  float ap = 0.f;
#pragma unroll
  for (int id = 0; id < IDN; ++id) {
    float rec = 0.f;
#pragma unroll
    for (int k = 0; k < ODH; ++k) rec = fmaf(h[k], wr[id][k], rec);
    ap = fmaf(rec, xn[id], ap);
  }
  const float af = ap + dpp_swap1(ap);                // full alpha(b,ic,oc)
  float asum = 0.f;
  const int gbase = grp * 20;
#pragma unroll
  for (int k = 0; k < OCN; ++k) asum += __shfl(af, gbase + 2 * k, 64);
  const float an = af * __builtin_amdgcn_rcpf(asum + EPS);

  // ---- block-level reduction over the 8 ic, then one atomic per slot ----
#pragma unroll
  for (int k = 0; k < ODH; ++k)
    red[w * 512 + k * 64 + l] = h[k] * an;

  __syncthreads();

  {
    const int k2 = threadIdx.x >> 6;   // 0..7
    const int l2 = threadIdx.x & 63;
    const int grp2 = l2 / 20;
    const int q2 = l2 % 20;
    const int oc2 = q2 >> 1;
    const int half2 = q2 & 1;
    const int b2 = bgrp * 3 + grp2;
    float s = 0.f;
#pragma unroll
    for (int ww = 0; ww < WPB; ++ww)
      s += red[ww * 512 + k2 * 64 + l2];
    if (grp2 < 3 && b2 < B_)
      atomicAdd(outg + (b2 * OCN + oc2) * ODN + half2 * ODH + k2, s);
  }
}

extern "C" void kernel_launch(void* const* d_in, const int* in_sizes, int n_in,
                              void* d_out, int out_size, void* d_ws, size_t ws_size,
                              hipStream_t stream) {
  const float* x = (const float*)d_in[0];
  const float* w = (const float*)d_in[1];
  float* out = (float*)d_out;
  (void)d_ws; (void)ws_size;

  hipMemsetAsync(out, 0, OUTN * sizeof(float), stream);
  caps_main<<<NBLK, 512, 0, stream>>>(x, w, out);
}

// Round 5
// 97.980 us; speedup vs baseline: 1.3463x; 1.3463x over previous
//
#include <hip/hip_runtime.h>

#define B_   32
#define ICN  1152
#define OCN  10
#define IDN  8
#define ODN  16
#define ODH  8                  // od half width (split across 2 lanes)
#define NIT  5
#define EPS  1e-20f
#define OUTN (B_ * OCN * ODN)   // 5120
#define BGRP 11                 // ceil(32 b / 3 groups per wave)
#define NBLK (BGRP * ICN)       // 12672 one-wave blocks

typedef float v4f __attribute__((ext_vector_type(4)));

// Pair-swap lanes (2k,2k+1) via DPP quad_perm [1,0,3,2] = 0xB1. Pure VALU.
__device__ __forceinline__ float dpp_swap1(float x) {
  return __int_as_float(__builtin_amdgcn_update_dpp(
      0, __float_as_int(x), 0xB1, 0xF, 0xF, true));
}

// ---------------------------------------------------------------------------
// R5 = R0 output structure (ws + reduce; the 256MiB ws poison-fill runs every
// iteration ANYWAY, so the workspace is free — and R3 proved the atomic-output
// variant costs +40us) + VOLATILE weight/x loads.
//
// Residency rationale: R3/R4 VGPR_Count=52 proves wr[8][8] was never
// register-resident — the compiler rematerialized the (readonly,noalias)
// global loads inside every NNMF phase, putting L1/L2 latency on the
// dependency chain 11 times per wave (VALUBusy 26%, latency-bound).
// Empty-asm pins produced bit-identical binaries (R4). volatile loads are
// the language-level guarantee: a volatile access cannot be duplicated, so
// each weight is loaded EXACTLY once and must live in VGPRs thereafter.
// Expected VGPR ~110-128, fits __launch_bounds__(64,4)'s 128-VGPR cap.
// ---------------------------------------------------------------------------
__global__ __launch_bounds__(64, 4) void caps_main(
    const float* __restrict__ xg, const float* __restrict__ wg,
    float* __restrict__ ws, float* __restrict__ outg, int atomic_out) {
  const int l = threadIdx.x;
  const int bid = blockIdx.x;
  const int ic = bid % ICN;      // same-ic blocks 1152 apart -> same XCD (1152%8==0)
  const int bgrp = bid / ICN;    // 0..10
  const int grp = l / 20;        // 0..3 (3 = idle lanes 60..63)
  const int q = l % 20;
  const int oc = q >> 1;         // 0..9
  const int half = q & 1;        // 0,1
  const int b = bgrp * 3 + grp;
  const bool valid = (grp < 3) && (b < B_);
  const int bb = (b < B_) ? b : (B_ - 1);   // clamp for loads only

  // ---- weights slice -> registers (volatile: loaded exactly once) ----
  float wr[IDN][ODH];
  {
    const float* wp = wg + ((size_t)ic * OCN + oc) * (IDN * ODN) + half * ODH;
#pragma unroll
    for (int id = 0; id < IDN; ++id) {
      const v4f v0 = *(const volatile v4f*)(wp + id * ODN);
      const v4f v1 = *(const volatile v4f*)(wp + id * ODN + 4);
      wr[id][0] = v0.x; wr[id][1] = v0.y; wr[id][2] = v0.z; wr[id][3] = v0.w;
      wr[id][4] = v1.x; wr[id][5] = v1.y; wr[id][6] = v1.z; wr[id][7] = v1.w;
    }
  }

  // ---- x[b,ic,:] normalized over id (volatile source loads) ----
  float xn[IDN];
  {
    const float* xp = xg + ((size_t)bb * ICN + ic) * IDN;
    const v4f a0 = ((const volatile v4f*)xp)[0];
    const v4f a1 = ((const volatile v4f*)xp)[1];
    xn[0] = a0.x; xn[1] = a0.y; xn[2] = a0.z; xn[3] = a0.w;
    xn[4] = a1.x; xn[5] = a1.y; xn[6] = a1.z; xn[7] = a1.w;
    const float s = ((xn[0] + xn[1]) + (xn[2] + xn[3])) +
                    ((xn[4] + xn[5]) + (xn[6] + xn[7]));
    const float r = __builtin_amdgcn_rcpf(s + EPS);
#pragma unroll
    for (int i = 0; i < IDN; ++i) xn[i] *= r;
  }

  // ---- NNMF iterations (phase-batched for ILP, DPP for pair reductions) ----
  float h[ODH];
#pragma unroll
  for (int k = 0; k < ODH; ++k) h[k] = 1.0f / ODN;

  for (int it = 0; it < NIT; ++it) {
    float pd[IDN];
#pragma unroll
    for (int id = 0; id < IDN; ++id) {
      float p = 0.f;
#pragma unroll
      for (int k = 0; k < ODH; ++k) p = fmaf(h[k], wr[id][k], p);
      pd[id] = p;
    }
    float tc[IDN];
#pragma unroll
    for (int id = 0; id < IDN; ++id) {
      const float den = pd[id] + dpp_swap1(pd[id]);   // full 16-od sum
      tc[id] = xn[id] * __builtin_amdgcn_rcpf(den + EPS);
    }
    float hacc[ODH];
#pragma unroll
    for (int k = 0; k < ODH; ++k) hacc[k] = wr[0][k] * tc[0];
#pragma unroll
    for (int id = 1; id < IDN; ++id)
#pragma unroll
      for (int k = 0; k < ODH; ++k) hacc[k] = fmaf(wr[id][k], tc[id], hacc[k]);
#pragma unroll
    for (int k = 0; k < ODH; ++k) h[k] *= hacc[k];
    const float ps = ((h[0] + h[1]) + (h[2] + h[3])) +
                     ((h[4] + h[5]) + (h[6] + h[7]));
    const float hs = ps + dpp_swap1(ps);              // full 16-od sum
    const float r = __builtin_amdgcn_rcpf(hs + EPS);
#pragma unroll
    for (int k = 0; k < ODH; ++k) h[k] *= r;
  }

  // ---- alpha = sum_id (sum_od h*w) * xn, normalized over oc ----
  float ap = 0.f;
#pragma unroll
  for (int id = 0; id < IDN; ++id) {
    float rec = 0.f;
#pragma unroll
    for (int k = 0; k < ODH; ++k) rec = fmaf(h[k], wr[id][k], rec);
    ap = fmaf(rec, xn[id], ap);
  }
  const float af = ap + dpp_swap1(ap);                // full alpha(b,ic,oc)
  float asum = 0.f;
  const int gbase = grp * 20;
#pragma unroll
  for (int k = 0; k < OCN; ++k) asum += __shfl(af, gbase + 2 * k, 64);
  const float an = af * __builtin_amdgcn_rcpf(asum + EPS);

  float o[ODH];
#pragma unroll
  for (int k = 0; k < ODH; ++k) o[k] = h[k] * an;

  if (valid) {
    if (!atomic_out) {
      float* dst = ws + (size_t)ic * OUTN + (bb * OCN + oc) * ODN + half * ODH;
      float4 v0, v1;
      v0.x = o[0]; v0.y = o[1]; v0.z = o[2]; v0.w = o[3];
      v1.x = o[4]; v1.y = o[5]; v1.z = o[6]; v1.w = o[7];
      ((float4*)dst)[0] = v0;
      ((float4*)dst)[1] = v1;
    } else {
      const int base = (bb * OCN + oc) * ODN + half * ODH;
#pragma unroll
      for (int k = 0; k < ODH; ++k) atomicAdd(outg + base + k, o[k]);
    }
  }
}

// ---------------------------------------------------------------------------
// Reduce: out[j] += sum_{r in my 36 rows} ws[r][j].
// grid = (5120/256, 32), block 256 -> 640 blocks / 2560 waves, 36 independent
// loads each (MLP), only 32 atomic contenders per address (out pre-zeroed).
// ---------------------------------------------------------------------------
#define RSPLIT 32
#define RROWS  (ICN / RSPLIT)   // 36
__global__ void caps_reduce(const float* __restrict__ ws, float* __restrict__ outg) {
  const int j = blockIdx.x * 256 + threadIdx.x;
  const int r0 = blockIdx.y * RROWS;
  float s = 0.f;
#pragma unroll
  for (int r = 0; r < RROWS; ++r) s += ws[(size_t)(r0 + r) * OUTN + j];
  atomicAdd(outg + j, s);
}

extern "C" void kernel_launch(void* const* d_in, const int* in_sizes, int n_in,
                              void* d_out, int out_size, void* d_ws, size_t ws_size,
                              hipStream_t stream) {
  const float* x = (const float*)d_in[0];
  const float* w = (const float*)d_in[1];
  float* out = (float*)d_out;
  float* ws = (float*)d_ws;

  hipMemsetAsync(out, 0, OUTN * sizeof(float), stream);

  const size_t need = (size_t)ICN * OUTN * sizeof(float);  // 23.6 MB

  if (ws_size >= need) {
    caps_main<<<NBLK, 64, 0, stream>>>(x, w, ws, out, 0);
    caps_reduce<<<dim3(OUTN / 256, RSPLIT), 256, 0, stream>>>(ws, out);
  } else {
    caps_main<<<NBLK, 64, 0, stream>>>(x, w, nullptr, out, 1);
  }
}

// Round 6
// 91.318 us; speedup vs baseline: 1.4446x; 1.0729x over previous
//
#include <hip/hip_runtime.h>

#define B_   32
#define ICN  1152
#define OCN  10
#define IDN  8
#define ODN  16
#define ODH  8                  // od half width (split across 2 lanes)
#define NIT  5
#define EPS  1e-20f
#define OUTN (B_ * OCN * ODN)   // 5120
#define BGRP 11                 // ceil(32 b / 3 groups per wave)
#define NBLK (BGRP * ICN)       // 12672 one-wave blocks

typedef float v4f __attribute__((ext_vector_type(4)));

// Pair-swap lanes (2k,2k+1) via DPP quad_perm [1,0,3,2] = 0xB1. Pure VALU.
__device__ __forceinline__ float dpp_swap1(float x) {
  return __int_as_float(__builtin_amdgcn_update_dpp(
      0, __float_as_int(x), 0xB1, 0xF, 0xF, true));
}

// Volatile-asm global load: the result register is produced by a volatile asm
// statement, which LLVM can neither rematerialize nor duplicate. This is the
// residency guarantee that R4's empty-asm pin and R5's volatile pointers
// failed to deliver (VGPR_Count stuck at 52 = weights re-fetched through
// L1/L2 inside every NNMF phase, latency on the dependency chain).
__device__ __forceinline__ v4f gload4(const float* p) {
  v4f r;
  asm volatile("global_load_dwordx4 %0, %1, off" : "=v"(r) : "v"(p));
  return r;
}

// ---------------------------------------------------------------------------
// R6 = R5 structure (ws + reduce output; phase-batched NNMF; DPP pair
// reductions) with TWO changes:
//   1. weights + x loaded via volatile inline-asm global_load_dwordx4 into
//      pinned v4f registers, one s_waitcnt vmcnt(0) + sched_barrier(0) fence
//      (rule #18) before first use;
//   2. __launch_bounds__(64, 2): 256-VGPR cap so the allocator KEEPS the
//      ~115 live registers instead of spilling to hold a 64-VGPR/8-wave
//      occupancy target. Natural occupancy becomes ~4 waves/SIMD, enough to
//      hide the single prologue load burst.
// Expected: VGPR ~100-130, caps_main drops from ~38us toward its ~12us
// VALU-issue floor.
// ---------------------------------------------------------------------------
__global__ __launch_bounds__(64, 2) void caps_main(
    const float* __restrict__ xg, const float* __restrict__ wg,
    float* __restrict__ ws, float* __restrict__ outg, int atomic_out) {
  const int l = threadIdx.x;
  const int bid = blockIdx.x;
  const int ic = bid % ICN;      // same-ic blocks 1152 apart -> same XCD (1152%8==0)
  const int bgrp = bid / ICN;    // 0..10
  const int grp = l / 20;        // 0..3 (3 = idle lanes 60..63)
  const int q = l % 20;
  const int oc = q >> 1;         // 0..9
  const int half = q & 1;        // 0,1
  const int b = bgrp * 3 + grp;
  const bool valid = (grp < 3) && (b < B_);
  const int bb = (b < B_) ? b : (B_ - 1);   // clamp for loads only

  // ---- weights slice + x -> pinned registers (16+2 asm loads, 1 waitcnt) ----
  v4f wv[2 * IDN];               // wv[2*id+j] = w[ic][oc][id][half*8 + 4j ..]
  {
    const float* wp = wg + ((size_t)ic * OCN + oc) * (IDN * ODN) + half * ODH;
#pragma unroll
    for (int id = 0; id < IDN; ++id) {
      wv[2 * id]     = gload4(wp + id * ODN);
      wv[2 * id + 1] = gload4(wp + id * ODN + 4);
    }
  }
  v4f xv0, xv1;
  {
    const float* xp = xg + ((size_t)bb * ICN + ic) * IDN;
    xv0 = gload4(xp);
    xv1 = gload4(xp + 4);
  }
  asm volatile("s_waitcnt vmcnt(0)" ::: "memory");
  __builtin_amdgcn_sched_barrier(0);

  // weight accessor: compile-time indices only (full unroll below)
#define W(id, k) (wv[2 * (id) + ((k) >> 2)][(k) & 3])

  // ---- x normalized over id ----
  float xn[IDN];
  {
    xn[0] = xv0.x; xn[1] = xv0.y; xn[2] = xv0.z; xn[3] = xv0.w;
    xn[4] = xv1.x; xn[5] = xv1.y; xn[6] = xv1.z; xn[7] = xv1.w;
    const float s = ((xn[0] + xn[1]) + (xn[2] + xn[3])) +
                    ((xn[4] + xn[5]) + (xn[6] + xn[7]));
    const float r = __builtin_amdgcn_rcpf(s + EPS);
#pragma unroll
    for (int i = 0; i < IDN; ++i) xn[i] *= r;
  }

  // ---- NNMF iterations (phase-batched for ILP, DPP for pair reductions) ----
  float h[ODH];
#pragma unroll
  for (int k = 0; k < ODH; ++k) h[k] = 1.0f / ODN;

  for (int it = 0; it < NIT; ++it) {
    float pd[IDN];
#pragma unroll
    for (int id = 0; id < IDN; ++id) {
      float p = 0.f;
#pragma unroll
      for (int k = 0; k < ODH; ++k) p = fmaf(h[k], W(id, k), p);
      pd[id] = p;
    }
    float tc[IDN];
#pragma unroll
    for (int id = 0; id < IDN; ++id) {
      const float den = pd[id] + dpp_swap1(pd[id]);   // full 16-od sum
      tc[id] = xn[id] * __builtin_amdgcn_rcpf(den + EPS);
    }
    float hacc[ODH];
#pragma unroll
    for (int k = 0; k < ODH; ++k) hacc[k] = W(0, k) * tc[0];
#pragma unroll
    for (int id = 1; id < IDN; ++id)
#pragma unroll
      for (int k = 0; k < ODH; ++k) hacc[k] = fmaf(W(id, k), tc[id], hacc[k]);
#pragma unroll
    for (int k = 0; k < ODH; ++k) h[k] *= hacc[k];
    const float ps = ((h[0] + h[1]) + (h[2] + h[3])) +
                     ((h[4] + h[5]) + (h[6] + h[7]));
    const float hs = ps + dpp_swap1(ps);              // full 16-od sum
    const float r = __builtin_amdgcn_rcpf(hs + EPS);
#pragma unroll
    for (int k = 0; k < ODH; ++k) h[k] *= r;
  }

  // ---- alpha = sum_id (sum_od h*w) * xn, normalized over oc ----
  float ap = 0.f;
#pragma unroll
  for (int id = 0; id < IDN; ++id) {
    float rec = 0.f;
#pragma unroll
    for (int k = 0; k < ODH; ++k) rec = fmaf(h[k], W(id, k), rec);
    ap = fmaf(rec, xn[id], ap);
  }
  const float af = ap + dpp_swap1(ap);                // full alpha(b,ic,oc)
  float asum = 0.f;
  const int gbase = grp * 20;
#pragma unroll
  for (int k = 0; k < OCN; ++k) asum += __shfl(af, gbase + 2 * k, 64);
  const float an = af * __builtin_amdgcn_rcpf(asum + EPS);

  float o[ODH];
#pragma unroll
  for (int k = 0; k < ODH; ++k) o[k] = h[k] * an;

  if (valid) {
    if (!atomic_out) {
      float* dst = ws + (size_t)ic * OUTN + (bb * OCN + oc) * ODN + half * ODH;
      float4 v0, v1;
      v0.x = o[0]; v0.y = o[1]; v0.z = o[2]; v0.w = o[3];
      v1.x = o[4]; v1.y = o[5]; v1.z = o[6]; v1.w = o[7];
      ((float4*)dst)[0] = v0;
      ((float4*)dst)[1] = v1;
    } else {
      const int base = (bb * OCN + oc) * ODN + half * ODH;
#pragma unroll
      for (int k = 0; k < ODH; ++k) atomicAdd(outg + base + k, o[k]);
    }
  }
#undef W
}

// ---------------------------------------------------------------------------
// Reduce: out[j] += sum_{r in my 36 rows} ws[r][j].
// grid = (5120/256, 32), block 256 -> 640 blocks / 2560 waves, 36 independent
// loads each (MLP), only 32 atomic contenders per address (out pre-zeroed).
// NOTE (R3 lesson): high-contention atomics are poison — 148 contenders in
// the atomic-output variant cost ~+40us. 32 contenders here is fine.
// ---------------------------------------------------------------------------
#define RSPLIT 32
#define RROWS  (ICN / RSPLIT)   // 36
__global__ void caps_reduce(const float* __restrict__ ws, float* __restrict__ outg) {
  const int j = blockIdx.x * 256 + threadIdx.x;
  const int r0 = blockIdx.y * RROWS;
  float s = 0.f;
#pragma unroll
  for (int r = 0; r < RROWS; ++r) s += ws[(size_t)(r0 + r) * OUTN + j];
  atomicAdd(outg + j, s);
}

extern "C" void kernel_launch(void* const* d_in, const int* in_sizes, int n_in,
                              void* d_out, int out_size, void* d_ws, size_t ws_size,
                              hipStream_t stream) {
  const float* x = (const float*)d_in[0];
  const float* w = (const float*)d_in[1];
  float* out = (float*)d_out;
  float* ws = (float*)d_ws;

  hipMemsetAsync(out, 0, OUTN * sizeof(float), stream);

  const size_t need = (size_t)ICN * OUTN * sizeof(float);  // 23.6 MB

  if (ws_size >= need) {
    caps_main<<<NBLK, 64, 0, stream>>>(x, w, ws, out, 0);
    caps_reduce<<<dim3(OUTN / 256, RSPLIT), 256, 0, stream>>>(ws, out);
  } else {
    caps_main<<<NBLK, 64, 0, stream>>>(x, w, nullptr, out, 1);
  }
}

// Round 7
// 91.199 us; speedup vs baseline: 1.4464x; 1.0013x over previous
//
#include <hip/hip_runtime.h>

#define B_   32
#define ICN  1152
#define OCN  10
#define IDN  8
#define ODN  16
#define ODH  8                  // od half width (split across 2 lanes)
#define NIT  5
#define EPS  1e-20f
#define OUTN (B_ * OCN * ODN)   // 5120
#define BGRP 11                 // ceil(32 b / 3 groups per wave)
#define NBLK (BGRP * ICN)       // 12672 one-wave blocks

typedef float v4f __attribute__((ext_vector_type(4)));

// Pair-swap lanes (2k,2k+1) via DPP quad_perm [1,0,3,2] = 0xB1. Pure VALU.
__device__ __forceinline__ float dpp_swap1(float x) {
  return __int_as_float(__builtin_amdgcn_update_dpp(
      0, __float_as_int(x), 0xB1, 0xF, 0xF, true));
}

// Volatile-asm global load: result not rematerializable/duplicable.
__device__ __forceinline__ v4f gload4(const float* p) {
  v4f r;
  asm volatile("global_load_dwordx4 %0, %1, off" : "=v"(r) : "v"(p));
  return r;
}

// ---------------------------------------------------------------------------
// R7 = R6 with ONE change: the NNMF it-loop is NOT unrolled (#pragma unroll 1).
//
// Theory: all six prior variants fully unrolled 5 iterations + alpha into
// ~16-35KB of straight-line code — at/past the 32KB I$. Every wave streams
// the whole body through instruction fetch (L2 refetch), capping VALU issue
// at ~27% (R3 counters) independent of data residency (R6 null), shuffle
// flavor (R1 null), and packing (R2 null). Rolling the it-loop shrinks the
// body ~5x so it fits I$; inner phases stay fully unrolled (compile-time
// indices into asm-pinned wv registers, ILP preserved).
// The atomic-output fallback lives in a SEPARATE kernel so caps_main's
// footprint stays minimal.
// ---------------------------------------------------------------------------
__global__ __launch_bounds__(64, 2) void caps_main(
    const float* __restrict__ xg, const float* __restrict__ wg,
    float* __restrict__ ws) {
  const int l = threadIdx.x;
  const int bid = blockIdx.x;
  const int ic = bid % ICN;      // same-ic blocks 1152 apart -> same XCD (1152%8==0)
  const int bgrp = bid / ICN;    // 0..10
  const int grp = l / 20;        // 0..3 (3 = idle lanes 60..63)
  const int q = l % 20;
  const int oc = q >> 1;         // 0..9
  const int half = q & 1;        // 0,1
  const int b = bgrp * 3 + grp;
  const bool valid = (grp < 3) && (b < B_);
  const int bb = (b < B_) ? b : (B_ - 1);   // clamp for loads only

  // ---- weights slice + x -> pinned registers (16+2 asm loads, 1 waitcnt) ----
  v4f wv[2 * IDN];               // wv[2*id+j] = w[ic][oc][id][half*8 + 4j ..]
  {
    const float* wp = wg + ((size_t)ic * OCN + oc) * (IDN * ODN) + half * ODH;
#pragma unroll
    for (int id = 0; id < IDN; ++id) {
      wv[2 * id]     = gload4(wp + id * ODN);
      wv[2 * id + 1] = gload4(wp + id * ODN + 4);
    }
  }
  v4f xv0, xv1;
  {
    const float* xp = xg + ((size_t)bb * ICN + ic) * IDN;
    xv0 = gload4(xp);
    xv1 = gload4(xp + 4);
  }
  asm volatile("s_waitcnt vmcnt(0)" ::: "memory");
  __builtin_amdgcn_sched_barrier(0);

#define W(id, k) (wv[2 * (id) + ((k) >> 2)][(k) & 3])

  // ---- x normalized over id ----
  float xn[IDN];
  {
    xn[0] = xv0.x; xn[1] = xv0.y; xn[2] = xv0.z; xn[3] = xv0.w;
    xn[4] = xv1.x; xn[5] = xv1.y; xn[6] = xv1.z; xn[7] = xv1.w;
    const float s = ((xn[0] + xn[1]) + (xn[2] + xn[3])) +
                    ((xn[4] + xn[5]) + (xn[6] + xn[7]));
    const float r = __builtin_amdgcn_rcpf(s + EPS);
#pragma unroll
    for (int i = 0; i < IDN; ++i) xn[i] *= r;
  }

  // ---- NNMF iterations: ROLLED outer loop (I$ footprint), unrolled phases ----
  float h[ODH];
#pragma unroll
  for (int k = 0; k < ODH; ++k) h[k] = 1.0f / ODN;

#pragma unroll 1
  for (int it = 0; it < NIT; ++it) {
    float pd[IDN];
#pragma unroll
    for (int id = 0; id < IDN; ++id) {
      float p = 0.f;
#pragma unroll
      for (int k = 0; k < ODH; ++k) p = fmaf(h[k], W(id, k), p);
      pd[id] = p;
    }
    float tc[IDN];
#pragma unroll
    for (int id = 0; id < IDN; ++id) {
      const float den = pd[id] + dpp_swap1(pd[id]);   // full 16-od sum
      tc[id] = xn[id] * __builtin_amdgcn_rcpf(den + EPS);
    }
    float hacc[ODH];
#pragma unroll
    for (int k = 0; k < ODH; ++k) hacc[k] = W(0, k) * tc[0];
#pragma unroll
    for (int id = 1; id < IDN; ++id)
#pragma unroll
      for (int k = 0; k < ODH; ++k) hacc[k] = fmaf(W(id, k), tc[id], hacc[k]);
#pragma unroll
    for (int k = 0; k < ODH; ++k) h[k] *= hacc[k];
    const float ps = ((h[0] + h[1]) + (h[2] + h[3])) +
                     ((h[4] + h[5]) + (h[6] + h[7]));
    const float hs = ps + dpp_swap1(ps);              // full 16-od sum
    const float r = __builtin_amdgcn_rcpf(hs + EPS);
#pragma unroll
    for (int k = 0; k < ODH; ++k) h[k] *= r;
  }

  // ---- alpha = sum_id (sum_od h*w) * xn, normalized over oc ----
  float ap = 0.f;
#pragma unroll
  for (int id = 0; id < IDN; ++id) {
    float rec = 0.f;
#pragma unroll
    for (int k = 0; k < ODH; ++k) rec = fmaf(h[k], W(id, k), rec);
    ap = fmaf(rec, xn[id], ap);
  }
  const float af = ap + dpp_swap1(ap);                // full alpha(b,ic,oc)
  float asum = 0.f;
  const int gbase = grp * 20;
#pragma unroll
  for (int k = 0; k < OCN; ++k) asum += __shfl(af, gbase + 2 * k, 64);
  const float an = af * __builtin_amdgcn_rcpf(asum + EPS);

  if (valid) {
    float* dst = ws + (size_t)ic * OUTN + (bb * OCN + oc) * ODN + half * ODH;
    float4 v0, v1;
    v0.x = h[0] * an; v0.y = h[1] * an; v0.z = h[2] * an; v0.w = h[3] * an;
    v1.x = h[4] * an; v1.y = h[5] * an; v1.z = h[6] * an; v1.w = h[7] * an;
    ((float4*)dst)[0] = v0;
    ((float4*)dst)[1] = v1;
  }
#undef W
}

// ---------------------------------------------------------------------------
// Fallback (ws too small): same math, atomic output. Separate kernel so it
// doesn't bloat caps_main's I$ footprint. Never dispatched in practice
// (harness ws is 256 MiB).
// ---------------------------------------------------------------------------
__global__ __launch_bounds__(64, 2) void caps_main_atomic(
    const float* __restrict__ xg, const float* __restrict__ wg,
    float* __restrict__ outg) {
  const int l = threadIdx.x;
  const int bid = blockIdx.x;
  const int ic = bid % ICN;
  const int bgrp = bid / ICN;
  const int grp = l / 20;
  const int q = l % 20;
  const int oc = q >> 1;
  const int half = q & 1;
  const int b = bgrp * 3 + grp;
  const bool valid = (grp < 3) && (b < B_);
  const int bb = (b < B_) ? b : (B_ - 1);

  float wr[IDN][ODH];
  {
    const float* wp = wg + ((size_t)ic * OCN + oc) * (IDN * ODN) + half * ODH;
#pragma unroll
    for (int id = 0; id < IDN; ++id) {
      const float4 v0 = *(const float4*)(wp + id * ODN);
      const float4 v1 = *(const float4*)(wp + id * ODN + 4);
      wr[id][0] = v0.x; wr[id][1] = v0.y; wr[id][2] = v0.z; wr[id][3] = v0.w;
      wr[id][4] = v1.x; wr[id][5] = v1.y; wr[id][6] = v1.z; wr[id][7] = v1.w;
    }
  }
  float xn[IDN];
  {
    const float* xp = xg + ((size_t)bb * ICN + ic) * IDN;
    const float4 a0 = ((const float4*)xp)[0];
    const float4 a1 = ((const float4*)xp)[1];
    xn[0] = a0.x; xn[1] = a0.y; xn[2] = a0.z; xn[3] = a0.w;
    xn[4] = a1.x; xn[5] = a1.y; xn[6] = a1.z; xn[7] = a1.w;
    float s = 0.f;
#pragma unroll
    for (int i = 0; i < IDN; ++i) s += xn[i];
    const float r = __builtin_amdgcn_rcpf(s + EPS);
#pragma unroll
    for (int i = 0; i < IDN; ++i) xn[i] *= r;
  }
  float h[ODH];
#pragma unroll
  for (int k = 0; k < ODH; ++k) h[k] = 1.0f / ODN;
#pragma unroll 1
  for (int it = 0; it < NIT; ++it) {
    float pd[IDN];
#pragma unroll
    for (int id = 0; id < IDN; ++id) {
      float p = 0.f;
#pragma unroll
      for (int k = 0; k < ODH; ++k) p = fmaf(h[k], wr[id][k], p);
      pd[id] = p;
    }
    float tc[IDN];
#pragma unroll
    for (int id = 0; id < IDN; ++id) {
      const float den = pd[id] + dpp_swap1(pd[id]);
      tc[id] = xn[id] * __builtin_amdgcn_rcpf(den + EPS);
    }
    float hacc[ODH];
#pragma unroll
    for (int k = 0; k < ODH; ++k) hacc[k] = wr[0][k] * tc[0];
#pragma unroll
    for (int id = 1; id < IDN; ++id)
#pragma unroll
      for (int k = 0; k < ODH; ++k) hacc[k] = fmaf(wr[id][k], tc[id], hacc[k]);
#pragma unroll
    for (int k = 0; k < ODH; ++k) h[k] *= hacc[k];
    float ps = 0.f;
#pragma unroll
    for (int k = 0; k < ODH; ++k) ps += h[k];
    const float hs = ps + dpp_swap1(ps);
    const float r = __builtin_amdgcn_rcpf(hs + EPS);
#pragma unroll
    for (int k = 0; k < ODH; ++k) h[k] *= r;
  }
  float ap = 0.f;
#pragma unroll
  for (int id = 0; id < IDN; ++id) {
    float rec = 0.f;
#pragma unroll
    for (int k = 0; k < ODH; ++k) rec = fmaf(h[k], wr[id][k], rec);
    ap = fmaf(rec, xn[id], ap);
  }
  const float af = ap + dpp_swap1(ap);
  float asum = 0.f;
  const int gbase = grp * 20;
#pragma unroll
  for (int k = 0; k < OCN; ++k) asum += __shfl(af, gbase + 2 * k, 64);
  const float an = af * __builtin_amdgcn_rcpf(asum + EPS);
  if (valid) {
    const int base = (bb * OCN + oc) * ODN + half * ODH;
#pragma unroll
    for (int k = 0; k < ODH; ++k) atomicAdd(outg + base + k, h[k] * an);
  }
}

// ---------------------------------------------------------------------------
// Reduce: out[j] += sum_{r in my 36 rows} ws[r][j].
// ---------------------------------------------------------------------------
#define RSPLIT 32
#define RROWS  (ICN / RSPLIT)   // 36
__global__ void caps_reduce(const float* __restrict__ ws, float* __restrict__ outg) {
  const int j = blockIdx.x * 256 + threadIdx.x;
  const int r0 = blockIdx.y * RROWS;
  float s = 0.f;
#pragma unroll
  for (int r = 0; r < RROWS; ++r) s += ws[(size_t)(r0 + r) * OUTN + j];
  atomicAdd(outg + j, s);
}

extern "C" void kernel_launch(void* const* d_in, const int* in_sizes, int n_in,
                              void* d_out, int out_size, void* d_ws, size_t ws_size,
                              hipStream_t stream) {
  const float* x = (const float*)d_in[0];
  const float* w = (const float*)d_in[1];
  float* out = (float*)d_out;
  float* ws = (float*)d_ws;

  hipMemsetAsync(out, 0, OUTN * sizeof(float), stream);

  const size_t need = (size_t)ICN * OUTN * sizeof(float);  // 23.6 MB

  if (ws_size >= need) {
    caps_main<<<NBLK, 64, 0, stream>>>(x, w, ws);
    caps_reduce<<<dim3(OUTN / 256, RSPLIT), 256, 0, stream>>>(ws, out);
  } else {
    caps_main_atomic<<<NBLK, 64, 0, stream>>>(x, w, out);
  }
}

// Round 8
// 89.800 us; speedup vs baseline: 1.4690x; 1.0156x over previous
//
#include <hip/hip_runtime.h>

#define B_   32
#define ICN  1152
#define OCN  10
#define IDN  8
#define ODN  16
#define ODH  8                  // od half width (split across 2 lanes)
#define NIT  5
#define EPS  1e-20f
#define OUTN (B_ * OCN * ODN)   // 5120
#define BGRP 11                 // ceil(32 b / 3 groups per wave)
#define GIC  2                  // ics per wave (partials summed in registers)
#define NGRP (ICN / GIC)        // 576 ws rows
#define NBLK (BGRP * NGRP)      // 6336 one-wave blocks

// Pair-swap lanes (2k,2k+1) via DPP quad_perm [1,0,3,2] = 0xB1. Pure VALU.
__device__ __forceinline__ float dpp_swap1(float x) {
  return __int_as_float(__builtin_amdgcn_update_dpp(
      0, __float_as_int(x), 0xB1, 0xF, 0xF, true));
}

// ---------------------------------------------------------------------------
// R8: attack the partial-sum tensor, not the instruction stream (6 nulls say
// the math core is what it is). out[b,oc,od] = sum_ic h*alpha, so per-ic
// partials are register-summable: each wave handles GIC=2 consecutive ics
// sequentially, accumulating oacc[] in registers, and writes ONE partial.
//   - ws shrinks 23.6 -> 11.8 MB (half the write-back, half the reduce read)
//   - reduce: 576 rows, grid(20 j-blocks x 16 row-chunks), 36 rows each,
//     16 atomic contenders/address (R3 lesson: contention is poison; 16 ok)
//   - caps_main: 6336 waves (6.2/SIMD avg), VALU total unchanged; plain
//     float4 loads (R6 proved pinning is perf-neutral; low VGPR = max occ)
// ---------------------------------------------------------------------------
__global__ __launch_bounds__(64, 4) void caps_main(
    const float* __restrict__ xg, const float* __restrict__ wg,
    float* __restrict__ ws) {
  const int l = threadIdx.x;
  const int bid = blockIdx.x;
  const int wgrp = bid % NGRP;   // same-wgrp blocks 576 apart -> same XCD (576%8==0)
  const int bgrp = bid / NGRP;   // 0..10
  const int grp = l / 20;        // 0..3 (3 = idle lanes 60..63)
  const int q = l % 20;
  const int oc = q >> 1;         // 0..9
  const int half = q & 1;        // 0,1
  const int b = bgrp * 3 + grp;
  const bool valid = (grp < 3) && (b < B_);
  const int bb = (b < B_) ? b : (B_ - 1);   // clamp for loads only
  const int ic0 = wgrp * GIC;

  float oacc[ODH];
#pragma unroll
  for (int k = 0; k < ODH; ++k) oacc[k] = 0.f;

#pragma unroll 1
  for (int g = 0; g < GIC; ++g) {
    const int ic = ic0 + g;

    // ---- weights slice: w[ic][oc][id][half*8 .. +8) ----
    float wr[IDN][ODH];
    {
      const float* wp = wg + ((size_t)ic * OCN + oc) * (IDN * ODN) + half * ODH;
#pragma unroll
      for (int id = 0; id < IDN; ++id) {
        const float4 v0 = *(const float4*)(wp + id * ODN);
        const float4 v1 = *(const float4*)(wp + id * ODN + 4);
        wr[id][0] = v0.x; wr[id][1] = v0.y; wr[id][2] = v0.z; wr[id][3] = v0.w;
        wr[id][4] = v1.x; wr[id][5] = v1.y; wr[id][6] = v1.z; wr[id][7] = v1.w;
      }
    }

    // ---- x[b,ic,:] normalized over id ----
    float xn[IDN];
    {
      const float* xp = xg + ((size_t)bb * ICN + ic) * IDN;
      const float4 a0 = ((const float4*)xp)[0];
      const float4 a1 = ((const float4*)xp)[1];
      xn[0] = a0.x; xn[1] = a0.y; xn[2] = a0.z; xn[3] = a0.w;
      xn[4] = a1.x; xn[5] = a1.y; xn[6] = a1.z; xn[7] = a1.w;
      const float s = ((xn[0] + xn[1]) + (xn[2] + xn[3])) +
                      ((xn[4] + xn[5]) + (xn[6] + xn[7]));
      const float r = __builtin_amdgcn_rcpf(s + EPS);
#pragma unroll
      for (int i = 0; i < IDN; ++i) xn[i] *= r;
    }

    // ---- NNMF iterations (phase-batched, DPP pair reductions) ----
    float h[ODH];
#pragma unroll
    for (int k = 0; k < ODH; ++k) h[k] = 1.0f / ODN;

#pragma unroll 1
    for (int it = 0; it < NIT; ++it) {
      float pd[IDN];
#pragma unroll
      for (int id = 0; id < IDN; ++id) {
        float p = 0.f;
#pragma unroll
        for (int k = 0; k < ODH; ++k) p = fmaf(h[k], wr[id][k], p);
        pd[id] = p;
      }
      float tc[IDN];
#pragma unroll
      for (int id = 0; id < IDN; ++id) {
        const float den = pd[id] + dpp_swap1(pd[id]);   // full 16-od sum
        tc[id] = xn[id] * __builtin_amdgcn_rcpf(den + EPS);
      }
      float hacc[ODH];
#pragma unroll
      for (int k = 0; k < ODH; ++k) hacc[k] = wr[0][k] * tc[0];
#pragma unroll
      for (int id = 1; id < IDN; ++id)
#pragma unroll
        for (int k = 0; k < ODH; ++k) hacc[k] = fmaf(wr[id][k], tc[id], hacc[k]);
#pragma unroll
      for (int k = 0; k < ODH; ++k) h[k] *= hacc[k];
      const float ps = ((h[0] + h[1]) + (h[2] + h[3])) +
                       ((h[4] + h[5]) + (h[6] + h[7]));
      const float hs = ps + dpp_swap1(ps);              // full 16-od sum
      const float r = __builtin_amdgcn_rcpf(hs + EPS);
#pragma unroll
      for (int k = 0; k < ODH; ++k) h[k] *= r;
    }

    // ---- alpha = sum_id (sum_od h*w) * xn, normalized over oc ----
    float ap = 0.f;
#pragma unroll
    for (int id = 0; id < IDN; ++id) {
      float rec = 0.f;
#pragma unroll
      for (int k = 0; k < ODH; ++k) rec = fmaf(h[k], wr[id][k], rec);
      ap = fmaf(rec, xn[id], ap);
    }
    const float af = ap + dpp_swap1(ap);                // full alpha(b,ic,oc)
    float asum = 0.f;
    const int gbase = grp * 20;
#pragma unroll
    for (int k = 0; k < OCN; ++k) asum += __shfl(af, gbase + 2 * k, 64);
    const float an = af * __builtin_amdgcn_rcpf(asum + EPS);

#pragma unroll
    for (int k = 0; k < ODH; ++k) oacc[k] = fmaf(h[k], an, oacc[k]);
  }

  if (valid) {
    float* dst = ws + (size_t)wgrp * OUTN + (bb * OCN + oc) * ODN + half * ODH;
    float4 v0, v1;
    v0.x = oacc[0]; v0.y = oacc[1]; v0.z = oacc[2]; v0.w = oacc[3];
    v1.x = oacc[4]; v1.y = oacc[5]; v1.z = oacc[6]; v1.w = oacc[7];
    ((float4*)dst)[0] = v0;
    ((float4*)dst)[1] = v1;
  }
}

// ---------------------------------------------------------------------------
// Fallback (ws too small): same math, atomic output, GIC ics per wave.
// Never dispatched in practice (harness ws is 256 MiB).
// ---------------------------------------------------------------------------
__global__ __launch_bounds__(64, 4) void caps_main_atomic(
    const float* __restrict__ xg, const float* __restrict__ wg,
    float* __restrict__ outg) {
  const int l = threadIdx.x;
  const int bid = blockIdx.x;
  const int wgrp = bid % NGRP;
  const int bgrp = bid / NGRP;
  const int grp = l / 20;
  const int q = l % 20;
  const int oc = q >> 1;
  const int half = q & 1;
  const int b = bgrp * 3 + grp;
  const bool valid = (grp < 3) && (b < B_);
  const int bb = (b < B_) ? b : (B_ - 1);
  const int ic0 = wgrp * GIC;

  float oacc[ODH];
#pragma unroll
  for (int k = 0; k < ODH; ++k) oacc[k] = 0.f;

#pragma unroll 1
  for (int g = 0; g < GIC; ++g) {
    const int ic = ic0 + g;
    float wr[IDN][ODH];
    {
      const float* wp = wg + ((size_t)ic * OCN + oc) * (IDN * ODN) + half * ODH;
#pragma unroll
      for (int id = 0; id < IDN; ++id) {
        const float4 v0 = *(const float4*)(wp + id * ODN);
        const float4 v1 = *(const float4*)(wp + id * ODN + 4);
        wr[id][0] = v0.x; wr[id][1] = v0.y; wr[id][2] = v0.z; wr[id][3] = v0.w;
        wr[id][4] = v1.x; wr[id][5] = v1.y; wr[id][6] = v1.z; wr[id][7] = v1.w;
      }
    }
    float xn[IDN];
    {
      const float* xp = xg + ((size_t)bb * ICN + ic) * IDN;
      const float4 a0 = ((const float4*)xp)[0];
      const float4 a1 = ((const float4*)xp)[1];
      xn[0] = a0.x; xn[1] = a0.y; xn[2] = a0.z; xn[3] = a0.w;
      xn[4] = a1.x; xn[5] = a1.y; xn[6] = a1.z; xn[7] = a1.w;
      float s = 0.f;
#pragma unroll
      for (int i = 0; i < IDN; ++i) s += xn[i];
      const float r = __builtin_amdgcn_rcpf(s + EPS);
#pragma unroll
      for (int i = 0; i < IDN; ++i) xn[i] *= r;
    }
    float h[ODH];
#pragma unroll
    for (int k = 0; k < ODH; ++k) h[k] = 1.0f / ODN;
#pragma unroll 1
    for (int it = 0; it < NIT; ++it) {
      float pd[IDN];
#pragma unroll
      for (int id = 0; id < IDN; ++id) {
        float p = 0.f;
#pragma unroll
        for (int k = 0; k < ODH; ++k) p = fmaf(h[k], wr[id][k], p);
        pd[id] = p;
      }
      float tc[IDN];
#pragma unroll
      for (int id = 0; id < IDN; ++id) {
        const float den = pd[id] + dpp_swap1(pd[id]);
        tc[id] = xn[id] * __builtin_amdgcn_rcpf(den + EPS);
      }
      float hacc[ODH];
#pragma unroll
      for (int k = 0; k < ODH; ++k) hacc[k] = wr[0][k] * tc[0];
#pragma unroll
      for (int id = 1; id < IDN; ++id)
#pragma unroll
        for (int k = 0; k < ODH; ++k) hacc[k] = fmaf(wr[id][k], tc[id], hacc[k]);
#pragma unroll
      for (int k = 0; k < ODH; ++k) h[k] *= hacc[k];
      float ps = 0.f;
#pragma unroll
      for (int k = 0; k < ODH; ++k) ps += h[k];
      const float hs = ps + dpp_swap1(ps);
      const float r = __builtin_amdgcn_rcpf(hs + EPS);
#pragma unroll
      for (int k = 0; k < ODH; ++k) h[k] *= r;
    }
    float ap = 0.f;
#pragma unroll
    for (int id = 0; id < IDN; ++id) {
      float rec = 0.f;
#pragma unroll
      for (int k = 0; k < ODH; ++k) rec = fmaf(h[k], wr[id][k], rec);
      ap = fmaf(rec, xn[id], ap);
    }
    const float af = ap + dpp_swap1(ap);
    float asum = 0.f;
    const int gbase = grp * 20;
#pragma unroll
    for (int k = 0; k < OCN; ++k) asum += __shfl(af, gbase + 2 * k, 64);
    const float an = af * __builtin_amdgcn_rcpf(asum + EPS);
#pragma unroll
    for (int k = 0; k < ODH; ++k) oacc[k] = fmaf(h[k], an, oacc[k]);
  }
  if (valid) {
    const int base = (bb * OCN + oc) * ODN + half * ODH;
#pragma unroll
    for (int k = 0; k < ODH; ++k) atomicAdd(outg + base + k, oacc[k]);
  }
}

// ---------------------------------------------------------------------------
// Reduce: out[j] += sum_{r in my 36 rows} ws[r][j], 576 rows total.
// grid = (5120/256, 16), block 256 -> 320 blocks, coalesced row reads,
// only 16 atomic contenders per address (out pre-zeroed).
// ---------------------------------------------------------------------------
#define RSPLIT 16
#define RROWS  (NGRP / RSPLIT)  // 36
__global__ void caps_reduce(const float* __restrict__ ws, float* __restrict__ outg) {
  const int j = blockIdx.x * 256 + threadIdx.x;
  const int r0 = blockIdx.y * RROWS;
  float s = 0.f;
#pragma unroll
  for (int r = 0; r < RROWS; ++r) s += ws[(size_t)(r0 + r) * OUTN + j];
  atomicAdd(outg + j, s);
}

extern "C" void kernel_launch(void* const* d_in, const int* in_sizes, int n_in,
                              void* d_out, int out_size, void* d_ws, size_t ws_size,
                              hipStream_t stream) {
  const float* x = (const float*)d_in[0];
  const float* w = (const float*)d_in[1];
  float* out = (float*)d_out;
  float* ws = (float*)d_ws;

  hipMemsetAsync(out, 0, OUTN * sizeof(float), stream);

  const size_t need = (size_t)NGRP * OUTN * sizeof(float);  // 11.8 MB

  if (ws_size >= need) {
    caps_main<<<NBLK, 64, 0, stream>>>(x, w, ws);
    caps_reduce<<<dim3(OUTN / 256, RSPLIT), 256, 0, stream>>>(ws, out);
  } else {
    caps_main_atomic<<<NBLK, 64, 0, stream>>>(x, w, out);
  }
}

// Round 10
// 89.257 us; speedup vs baseline: 1.4779x; 1.0061x over previous
//
#include <hip/hip_runtime.h>

#define B_   32
#define ICN  1152
#define OCN  10
#define IDN  8
#define ODN  16
#define ODH  8                  // od half width (split across 2 lanes)
#define ODP  4                  // od pairs per lane (packed fp32)
#define NIT  5
#define EPS  1e-20f
#define OUTN (B_ * OCN * ODN)   // 5120
#define BGRP 11                 // ceil(32 b / 3 groups per wave)
#define GIC  2                  // ics per wave (partials summed in registers)
#define NGRP (ICN / GIC)        // 576 ws rows
#define NBLK (BGRP * NGRP)      // 6336 one-wave blocks

typedef float v2f __attribute__((ext_vector_type(2)));

// Pair-swap lanes (2k,2k+1) via DPP quad_perm [1,0,3,2] = 0xB1. Pure VALU.
__device__ __forceinline__ float dpp_swap1(float x) {
  return __int_as_float(__builtin_amdgcn_update_dpp(
      0, __float_as_int(x), 0xB1, 0xF, 0xF, true));
}

// ---- VOP3P packed fp32 via asm (backend cannot scalarize) ----
// R9 lesson: ALL VOP3P f32 sources must be 64-bit VGPR PAIRS — a lone v-reg
// with op_sel_hi does not assemble. Scalar broadcasts are materialized as
// {b,b} pairs in C (1 v_mov each, negligible vs the saved FMA issues).
__device__ __forceinline__ v2f pk_fma(v2f a, v2f b, v2f c) {
  v2f d;
  asm("v_pk_fma_f32 %0, %1, %2, %3" : "=v"(d) : "v"(a), "v"(b), "v"(c));
  return d;
}
__device__ __forceinline__ v2f pk_mul(v2f a, v2f b) {
  v2f d;
  asm("v_pk_mul_f32 %0, %1, %2" : "=v"(d) : "v"(a), "v"(b));
  return d;
}
__device__ __forceinline__ v2f pk_add(v2f a, v2f b) {
  v2f d;
  asm("v_pk_add_f32 %0, %1, %2" : "=v"(d) : "v"(a), "v"(b));
  return d;
}
__device__ __forceinline__ v2f pk_bc(float b) {
  v2f r; r.x = b; r.y = b; return r;
}

// ---------------------------------------------------------------------------
// R10 = R9 with the assembler fix. Theory unchanged: after 8 rounds,
// caps_main (~40us) is invariant to occupancy (R0 12.4 vs R8 6.2 waves/SIMD),
// residency (R6 asm-pinned), I$ (R7), shuffle flavor (R1), packing (R2) —
// the signature of an ISSUE-COUNT-bound kernel. Every prior experiment held
// the VALU instruction count constant; this one cuts it ~35% by packing the
// od dimension into v_pk_{fma,mul,add}_f32 pairs. Structure identical to R8
// (GIC=2, ws+reduce output).
// ---------------------------------------------------------------------------
__global__ __launch_bounds__(64, 4) void caps_main(
    const float* __restrict__ xg, const float* __restrict__ wg,
    float* __restrict__ ws) {
  const int l = threadIdx.x;
  const int bid = blockIdx.x;
  const int wgrp = bid % NGRP;   // same-wgrp blocks 576 apart -> same XCD (576%8==0)
  const int bgrp = bid / NGRP;   // 0..10
  const int grp = l / 20;        // 0..3 (3 = idle lanes 60..63)
  const int q = l % 20;
  const int oc = q >> 1;         // 0..9
  const int half = q & 1;        // 0,1
  const int b = bgrp * 3 + grp;
  const bool valid = (grp < 3) && (b < B_);
  const int bb = (b < B_) ? b : (B_ - 1);   // clamp for loads only
  const int ic0 = wgrp * GIC;

  v2f oacc[ODP];
#pragma unroll
  for (int j = 0; j < ODP; ++j) oacc[j] = (v2f){0.f, 0.f};

#pragma unroll 1
  for (int g = 0; g < GIC; ++g) {
    const int ic = ic0 + g;

    // ---- weights slice as od-pairs: w2[id][j] = w[ic][oc][id][half*8+2j..] ----
    v2f w2[IDN][ODP];
    {
      const float* wp = wg + ((size_t)ic * OCN + oc) * (IDN * ODN) + half * ODH;
#pragma unroll
      for (int id = 0; id < IDN; ++id) {
        const float4 v0 = *(const float4*)(wp + id * ODN);
        const float4 v1 = *(const float4*)(wp + id * ODN + 4);
        w2[id][0] = (v2f){v0.x, v0.y};
        w2[id][1] = (v2f){v0.z, v0.w};
        w2[id][2] = (v2f){v1.x, v1.y};
        w2[id][3] = (v2f){v1.z, v1.w};
      }
    }

    // ---- x[b,ic,:] normalized over id ----
    float xn[IDN];
    {
      const float* xp = xg + ((size_t)bb * ICN + ic) * IDN;
      const float4 a0 = ((const float4*)xp)[0];
      const float4 a1 = ((const float4*)xp)[1];
      xn[0] = a0.x; xn[1] = a0.y; xn[2] = a0.z; xn[3] = a0.w;
      xn[4] = a1.x; xn[5] = a1.y; xn[6] = a1.z; xn[7] = a1.w;
      const float s = ((xn[0] + xn[1]) + (xn[2] + xn[3])) +
                      ((xn[4] + xn[5]) + (xn[6] + xn[7]));
      const float r = __builtin_amdgcn_rcpf(s + EPS);
#pragma unroll
      for (int i = 0; i < IDN; ++i) xn[i] *= r;
    }

    // ---- NNMF iterations (packed od-pairs, DPP cross-half reductions) ----
    v2f h2[ODP];
#pragma unroll
    for (int j = 0; j < ODP; ++j) h2[j] = (v2f){1.0f / ODN, 1.0f / ODN};

#pragma unroll 1
    for (int it = 0; it < NIT; ++it) {
      // phase 1+2: per-id packed dot -> den -> tc
      float tc[IDN];
#pragma unroll
      for (int id = 0; id < IDN; ++id) {
        v2f p2 = pk_mul(h2[3], w2[id][3]);
        p2 = pk_fma(h2[2], w2[id][2], p2);
        p2 = pk_fma(h2[1], w2[id][1], p2);
        p2 = pk_fma(h2[0], w2[id][0], p2);
        const float p = p2.x + p2.y;
        const float den = p + dpp_swap1(p);             // full 16-od sum
        tc[id] = xn[id] * __builtin_amdgcn_rcpf(den + EPS);
      }
      // phase 3: hacc[j] = sum_id w2[id][j] * tc[id]  (broadcast pairs)
      v2f hacc[ODP];
      {
        const v2f t0 = pk_bc(tc[0]);
#pragma unroll
        for (int j = 0; j < ODP; ++j) hacc[j] = pk_mul(w2[0][j], t0);
      }
#pragma unroll
      for (int id = 1; id < IDN; ++id) {
        const v2f ti = pk_bc(tc[id]);
#pragma unroll
        for (int j = 0; j < ODP; ++j)
          hacc[j] = pk_fma(w2[id][j], ti, hacc[j]);
      }
      // h update + normalize over od
#pragma unroll
      for (int j = 0; j < ODP; ++j) h2[j] = pk_mul(h2[j], hacc[j]);
      const v2f s2 = pk_add(pk_add(h2[0], h2[1]), pk_add(h2[2], h2[3]));
      const float ps = s2.x + s2.y;
      const float hs = ps + dpp_swap1(ps);              // full 16-od sum
      const v2f r2 = pk_bc(__builtin_amdgcn_rcpf(hs + EPS));
#pragma unroll
      for (int j = 0; j < ODP; ++j) h2[j] = pk_mul(h2[j], r2);
    }

    // ---- alpha = sum_id (sum_od h*w) * xn, normalized over oc ----
    float ap = 0.f;
#pragma unroll
    for (int id = 0; id < IDN; ++id) {
      v2f r2 = pk_mul(h2[3], w2[id][3]);
      r2 = pk_fma(h2[2], w2[id][2], r2);
      r2 = pk_fma(h2[1], w2[id][1], r2);
      r2 = pk_fma(h2[0], w2[id][0], r2);
      ap = fmaf(r2.x + r2.y, xn[id], ap);
    }
    const float af = ap + dpp_swap1(ap);                // full alpha(b,ic,oc)
    float asum = 0.f;
    const int gbase = grp * 20;
#pragma unroll
    for (int k = 0; k < OCN; ++k) asum += __shfl(af, gbase + 2 * k, 64);
    const float an = af * __builtin_amdgcn_rcpf(asum + EPS);

    const v2f an2 = pk_bc(an);
#pragma unroll
    for (int j = 0; j < ODP; ++j) oacc[j] = pk_fma(h2[j], an2, oacc[j]);
  }

  if (valid) {
    float* dst = ws + (size_t)wgrp * OUTN + (bb * OCN + oc) * ODN + half * ODH;
    float4 v0, v1;
    v0.x = oacc[0].x; v0.y = oacc[0].y; v0.z = oacc[1].x; v0.w = oacc[1].y;
    v1.x = oacc[2].x; v1.y = oacc[2].y; v1.z = oacc[3].x; v1.w = oacc[3].y;
    ((float4*)dst)[0] = v0;
    ((float4*)dst)[1] = v1;
  }
}

// ---------------------------------------------------------------------------
// Fallback (ws too small): scalar math, atomic output. Never dispatched in
// practice (harness ws is 256 MiB).
// ---------------------------------------------------------------------------
__global__ __launch_bounds__(64, 4) void caps_main_atomic(
    const float* __restrict__ xg, const float* __restrict__ wg,
    float* __restrict__ outg) {
  const int l = threadIdx.x;
  const int bid = blockIdx.x;
  const int wgrp = bid % NGRP;
  const int bgrp = bid / NGRP;
  const int grp = l / 20;
  const int q = l % 20;
  const int oc = q >> 1;
  const int half = q & 1;
  const int b = bgrp * 3 + grp;
  const bool valid = (grp < 3) && (b < B_);
  const int bb = (b < B_) ? b : (B_ - 1);
  const int ic0 = wgrp * GIC;

  float oacc[ODH];
#pragma unroll
  for (int k = 0; k < ODH; ++k) oacc[k] = 0.f;

#pragma unroll 1
  for (int g = 0; g < GIC; ++g) {
    const int ic = ic0 + g;
    float wr[IDN][ODH];
    {
      const float* wp = wg + ((size_t)ic * OCN + oc) * (IDN * ODN) + half * ODH;
#pragma unroll
      for (int id = 0; id < IDN; ++id) {
        const float4 v0 = *(const float4*)(wp + id * ODN);
        const float4 v1 = *(const float4*)(wp + id * ODN + 4);
        wr[id][0] = v0.x; wr[id][1] = v0.y; wr[id][2] = v0.z; wr[id][3] = v0.w;
        wr[id][4] = v1.x; wr[id][5] = v1.y; wr[id][6] = v1.z; wr[id][7] = v1.w;
      }
    }
    float xn[IDN];
    {
      const float* xp = xg + ((size_t)bb * ICN + ic) * IDN;
      const float4 a0 = ((const float4*)xp)[0];
      const float4 a1 = ((const float4*)xp)[1];
      xn[0] = a0.x; xn[1] = a0.y; xn[2] = a0.z; xn[3] = a0.w;
      xn[4] = a1.x; xn[5] = a1.y; xn[6] = a1.z; xn[7] = a1.w;
      float s = 0.f;
#pragma unroll
      for (int i = 0; i < IDN; ++i) s += xn[i];
      const float r = __builtin_amdgcn_rcpf(s + EPS);
#pragma unroll
      for (int i = 0; i < IDN; ++i) xn[i] *= r;
    }
    float h[ODH];
#pragma unroll
    for (int k = 0; k < ODH; ++k) h[k] = 1.0f / ODN;
#pragma unroll 1
    for (int it = 0; it < NIT; ++it) {
      float pd[IDN];
#pragma unroll
      for (int id = 0; id < IDN; ++id) {
        float p = 0.f;
#pragma unroll
        for (int k = 0; k < ODH; ++k) p = fmaf(h[k], wr[id][k], p);
        pd[id] = p;
      }
      float tc[IDN];
#pragma unroll
      for (int id = 0; id < IDN; ++id) {
        const float den = pd[id] + dpp_swap1(pd[id]);
        tc[id] = xn[id] * __builtin_amdgcn_rcpf(den + EPS);
      }
      float hacc[ODH];
#pragma unroll
      for (int k = 0; k < ODH; ++k) hacc[k] = wr[0][k] * tc[0];
#pragma unroll
      for (int id = 1; id < IDN; ++id)
#pragma unroll
        for (int k = 0; k < ODH; ++k) hacc[k] = fmaf(wr[id][k], tc[id], hacc[k]);
#pragma unroll
      for (int k = 0; k < ODH; ++k) h[k] *= hacc[k];
      float ps = 0.f;
#pragma unroll
      for (int k = 0; k < ODH; ++k) ps += h[k];
      const float hs = ps + dpp_swap1(ps);
      const float r = __builtin_amdgcn_rcpf(hs + EPS);
#pragma unroll
      for (int k = 0; k < ODH; ++k) h[k] *= r;
    }
    float ap = 0.f;
#pragma unroll
    for (int id = 0; id < IDN; ++id) {
      float rec = 0.f;
#pragma unroll
      for (int k = 0; k < ODH; ++k) rec = fmaf(h[k], wr[id][k], rec);
      ap = fmaf(rec, xn[id], ap);
    }
    const float af = ap + dpp_swap1(ap);
    float asum = 0.f;
    const int gbase = grp * 20;
#pragma unroll
    for (int k = 0; k < OCN; ++k) asum += __shfl(af, gbase + 2 * k, 64);
    const float an = af * __builtin_amdgcn_rcpf(asum + EPS);
#pragma unroll
    for (int k = 0; k < ODH; ++k) oacc[k] = fmaf(h[k], an, oacc[k]);
  }
  if (valid) {
    const int base = (bb * OCN + oc) * ODN + half * ODH;
#pragma unroll
    for (int k = 0; k < ODH; ++k) atomicAdd(outg + base + k, oacc[k]);
  }
}

// ---------------------------------------------------------------------------
// Reduce: out[j] += sum_{r in my 36 rows} ws[r][j], 576 rows total.
// grid = (5120/256, 16), block 256; 16 atomic contenders per address.
// ---------------------------------------------------------------------------
#define RSPLIT 16
#define RROWS  (NGRP / RSPLIT)  // 36
__global__ void caps_reduce(const float* __restrict__ ws, float* __restrict__ outg) {
  const int j = blockIdx.x * 256 + threadIdx.x;
  const int r0 = blockIdx.y * RROWS;
  float s = 0.f;
#pragma unroll
  for (int r = 0; r < RROWS; ++r) s += ws[(size_t)(r0 + r) * OUTN + j];
  atomicAdd(outg + j, s);
}

extern "C" void kernel_launch(void* const* d_in, const int* in_sizes, int n_in,
                              void* d_out, int out_size, void* d_ws, size_t ws_size,
                              hipStream_t stream) {
  const float* x = (const float*)d_in[0];
  const float* w = (const float*)d_in[1];
  float* out = (float*)d_out;
  float* ws = (float*)d_ws;

  hipMemsetAsync(out, 0, OUTN * sizeof(float), stream);

  const size_t need = (size_t)NGRP * OUTN * sizeof(float);  // 11.8 MB

  if (ws_size >= need) {
    caps_main<<<NBLK, 64, 0, stream>>>(x, w, ws);
    caps_reduce<<<dim3(OUTN / 256, RSPLIT), 256, 0, stream>>>(ws, out);
  } else {
    caps_main_atomic<<<NBLK, 64, 0, stream>>>(x, w, out);
  }
}

// Round 11
// 89.096 us; speedup vs baseline: 1.4806x; 1.0018x over previous
//
#include <hip/hip_runtime.h>

#define B_   32
#define ICN  1152
#define OCN  10
#define IDN  8
#define ODN  16
#define ODH  8                  // od half width (split across 2 lanes)
#define ODP  4                  // od pairs per lane (packed fp32)
#define NIT  5
#define EPS  1e-20f
#define OUTN (B_ * OCN * ODN)   // 5120
#define BGRP 11                 // ceil(32 b / 3 groups per wave)
#define GIC  4                  // ics per wave (partials summed in registers)
#define NGRP (ICN / GIC)        // 288 ws rows
#define NBLK (BGRP * NGRP)      // 3168 one-wave blocks

typedef float v2f __attribute__((ext_vector_type(2)));

// Pair-swap lanes (2k,2k+1) via DPP quad_perm [1,0,3,2] = 0xB1. Pure VALU.
__device__ __forceinline__ float dpp_swap1(float x) {
  return __int_as_float(__builtin_amdgcn_update_dpp(
      0, __float_as_int(x), 0xB1, 0xF, 0xF, true));
}

// ---- VOP3P packed fp32 via asm. R9 lesson: all sources must be VGPR pairs.
__device__ __forceinline__ v2f pk_fma(v2f a, v2f b, v2f c) {
  v2f d;
  asm("v_pk_fma_f32 %0, %1, %2, %3" : "=v"(d) : "v"(a), "v"(b), "v"(c));
  return d;
}
__device__ __forceinline__ v2f pk_mul(v2f a, v2f b) {
  v2f d;
  asm("v_pk_mul_f32 %0, %1, %2" : "=v"(d) : "v"(a), "v"(b));
  return d;
}
__device__ __forceinline__ v2f pk_add(v2f a, v2f b) {
  v2f d;
  asm("v_pk_add_f32 %0, %1, %2" : "=v"(d) : "v"(a), "v"(b));
  return d;
}
__device__ __forceinline__ v2f pk_bc(float b) {
  v2f r; r.x = b; r.y = b; return r;
}

// ---------------------------------------------------------------------------
// R11: stack the only empirically-positive lever (R7->R8: fewer waves via
// register-accumulated ic grouping, smaller ws) — GIC 2 -> 4. The g-loop is
// FULLY UNROLLED so the compiler can pipeline g+1's weight loads under g's
// compute (R7 proved I$ footprint is free). Packed od-pair math kept from
// R10 (numerics verified, absmax 0.0). Reduce: 288 rows, RSPLIT=8 -> 160
// blocks, 8 atomic contenders/address.
// Falsified-and-closed theory classes (10 rounds): shuffle latency (R1),
// WG dispatch rate (R2), register residency (R6, asm-pinned), I$ (R7),
// VALU instruction count (R10), atomic-output (R3: -40us regression).
// ---------------------------------------------------------------------------
__global__ __launch_bounds__(64, 4) void caps_main(
    const float* __restrict__ xg, const float* __restrict__ wg,
    float* __restrict__ ws) {
  const int l = threadIdx.x;
  const int bid = blockIdx.x;
  const int wgrp = bid % NGRP;   // same-wgrp blocks 288 apart -> same XCD (288%8==0)
  const int bgrp = bid / NGRP;   // 0..10
  const int grp = l / 20;        // 0..3 (3 = idle lanes 60..63)
  const int q = l % 20;
  const int oc = q >> 1;         // 0..9
  const int half = q & 1;        // 0,1
  const int b = bgrp * 3 + grp;
  const bool valid = (grp < 3) && (b < B_);
  const int bb = (b < B_) ? b : (B_ - 1);   // clamp for loads only
  const int ic0 = wgrp * GIC;

  v2f oacc[ODP];
#pragma unroll
  for (int j = 0; j < ODP; ++j) oacc[j] = (v2f){0.f, 0.f};

#pragma unroll
  for (int g = 0; g < GIC; ++g) {
    const int ic = ic0 + g;

    // ---- weights slice as od-pairs: w2[id][j] = w[ic][oc][id][half*8+2j..] ----
    v2f w2[IDN][ODP];
    {
      const float* wp = wg + ((size_t)ic * OCN + oc) * (IDN * ODN) + half * ODH;
#pragma unroll
      for (int id = 0; id < IDN; ++id) {
        const float4 v0 = *(const float4*)(wp + id * ODN);
        const float4 v1 = *(const float4*)(wp + id * ODN + 4);
        w2[id][0] = (v2f){v0.x, v0.y};
        w2[id][1] = (v2f){v0.z, v0.w};
        w2[id][2] = (v2f){v1.x, v1.y};
        w2[id][3] = (v2f){v1.z, v1.w};
      }
    }

    // ---- x[b,ic,:] normalized over id ----
    float xn[IDN];
    {
      const float* xp = xg + ((size_t)bb * ICN + ic) * IDN;
      const float4 a0 = ((const float4*)xp)[0];
      const float4 a1 = ((const float4*)xp)[1];
      xn[0] = a0.x; xn[1] = a0.y; xn[2] = a0.z; xn[3] = a0.w;
      xn[4] = a1.x; xn[5] = a1.y; xn[6] = a1.z; xn[7] = a1.w;
      const float s = ((xn[0] + xn[1]) + (xn[2] + xn[3])) +
                      ((xn[4] + xn[5]) + (xn[6] + xn[7]));
      const float r = __builtin_amdgcn_rcpf(s + EPS);
#pragma unroll
      for (int i = 0; i < IDN; ++i) xn[i] *= r;
    }

    // ---- NNMF iterations (packed od-pairs, DPP cross-half reductions) ----
    v2f h2[ODP];
#pragma unroll
    for (int j = 0; j < ODP; ++j) h2[j] = (v2f){1.0f / ODN, 1.0f / ODN};

#pragma unroll 1
    for (int it = 0; it < NIT; ++it) {
      // phase 1+2: per-id packed dot -> den -> tc
      float tc[IDN];
#pragma unroll
      for (int id = 0; id < IDN; ++id) {
        v2f p2 = pk_mul(h2[3], w2[id][3]);
        p2 = pk_fma(h2[2], w2[id][2], p2);
        p2 = pk_fma(h2[1], w2[id][1], p2);
        p2 = pk_fma(h2[0], w2[id][0], p2);
        const float p = p2.x + p2.y;
        const float den = p + dpp_swap1(p);             // full 16-od sum
        tc[id] = xn[id] * __builtin_amdgcn_rcpf(den + EPS);
      }
      // phase 3: hacc[j] = sum_id w2[id][j] * tc[id]  (broadcast pairs)
      v2f hacc[ODP];
      {
        const v2f t0 = pk_bc(tc[0]);
#pragma unroll
        for (int j = 0; j < ODP; ++j) hacc[j] = pk_mul(w2[0][j], t0);
      }
#pragma unroll
      for (int id = 1; id < IDN; ++id) {
        const v2f ti = pk_bc(tc[id]);
#pragma unroll
        for (int j = 0; j < ODP; ++j)
          hacc[j] = pk_fma(w2[id][j], ti, hacc[j]);
      }
      // h update + normalize over od
#pragma unroll
      for (int j = 0; j < ODP; ++j) h2[j] = pk_mul(h2[j], hacc[j]);
      const v2f s2 = pk_add(pk_add(h2[0], h2[1]), pk_add(h2[2], h2[3]));
      const float ps = s2.x + s2.y;
      const float hs = ps + dpp_swap1(ps);              // full 16-od sum
      const v2f r2 = pk_bc(__builtin_amdgcn_rcpf(hs + EPS));
#pragma unroll
      for (int j = 0; j < ODP; ++j) h2[j] = pk_mul(h2[j], r2);
    }

    // ---- alpha = sum_id (sum_od h*w) * xn, normalized over oc ----
    float ap = 0.f;
#pragma unroll
    for (int id = 0; id < IDN; ++id) {
      v2f r2 = pk_mul(h2[3], w2[id][3]);
      r2 = pk_fma(h2[2], w2[id][2], r2);
      r2 = pk_fma(h2[1], w2[id][1], r2);
      r2 = pk_fma(h2[0], w2[id][0], r2);
      ap = fmaf(r2.x + r2.y, xn[id], ap);
    }
    const float af = ap + dpp_swap1(ap);                // full alpha(b,ic,oc)
    float asum = 0.f;
    const int gbase = grp * 20;
#pragma unroll
    for (int k = 0; k < OCN; ++k) asum += __shfl(af, gbase + 2 * k, 64);
    const float an = af * __builtin_amdgcn_rcpf(asum + EPS);

    const v2f an2 = pk_bc(an);
#pragma unroll
    for (int j = 0; j < ODP; ++j) oacc[j] = pk_fma(h2[j], an2, oacc[j]);
  }

  if (valid) {
    float* dst = ws + (size_t)wgrp * OUTN + (bb * OCN + oc) * ODN + half * ODH;
    float4 v0, v1;
    v0.x = oacc[0].x; v0.y = oacc[0].y; v0.z = oacc[1].x; v0.w = oacc[1].y;
    v1.x = oacc[2].x; v1.y = oacc[2].y; v1.z = oacc[3].x; v1.w = oacc[3].y;
    ((float4*)dst)[0] = v0;
    ((float4*)dst)[1] = v1;
  }
}

// ---------------------------------------------------------------------------
// Fallback (ws too small): scalar math, atomic output. Never dispatched in
// practice (harness ws is 256 MiB).
// ---------------------------------------------------------------------------
__global__ __launch_bounds__(64, 4) void caps_main_atomic(
    const float* __restrict__ xg, const float* __restrict__ wg,
    float* __restrict__ outg) {
  const int l = threadIdx.x;
  const int bid = blockIdx.x;
  const int wgrp = bid % NGRP;
  const int bgrp = bid / NGRP;
  const int grp = l / 20;
  const int q = l % 20;
  const int oc = q >> 1;
  const int half = q & 1;
  const int b = bgrp * 3 + grp;
  const bool valid = (grp < 3) && (b < B_);
  const int bb = (b < B_) ? b : (B_ - 1);
  const int ic0 = wgrp * GIC;

  float oacc[ODH];
#pragma unroll
  for (int k = 0; k < ODH; ++k) oacc[k] = 0.f;

#pragma unroll 1
  for (int g = 0; g < GIC; ++g) {
    const int ic = ic0 + g;
    float wr[IDN][ODH];
    {
      const float* wp = wg + ((size_t)ic * OCN + oc) * (IDN * ODN) + half * ODH;
#pragma unroll
      for (int id = 0; id < IDN; ++id) {
        const float4 v0 = *(const float4*)(wp + id * ODN);
        const float4 v1 = *(const float4*)(wp + id * ODN + 4);
        wr[id][0] = v0.x; wr[id][1] = v0.y; wr[id][2] = v0.z; wr[id][3] = v0.w;
        wr[id][4] = v1.x; wr[id][5] = v1.y; wr[id][6] = v1.z; wr[id][7] = v1.w;
      }
    }
    float xn[IDN];
    {
      const float* xp = xg + ((size_t)bb * ICN + ic) * IDN;
      const float4 a0 = ((const float4*)xp)[0];
      const float4 a1 = ((const float4*)xp)[1];
      xn[0] = a0.x; xn[1] = a0.y; xn[2] = a0.z; xn[3] = a0.w;
      xn[4] = a1.x; xn[5] = a1.y; xn[6] = a1.z; xn[7] = a1.w;
      float s = 0.f;
#pragma unroll
      for (int i = 0; i < IDN; ++i) s += xn[i];
      const float r = __builtin_amdgcn_rcpf(s + EPS);
#pragma unroll
      for (int i = 0; i < IDN; ++i) xn[i] *= r;
    }
    float h[ODH];
#pragma unroll
    for (int k = 0; k < ODH; ++k) h[k] = 1.0f / ODN;
#pragma unroll 1
    for (int it = 0; it < NIT; ++it) {
      float pd[IDN];
#pragma unroll
      for (int id = 0; id < IDN; ++id) {
        float p = 0.f;
#pragma unroll
        for (int k = 0; k < ODH; ++k) p = fmaf(h[k], wr[id][k], p);
        pd[id] = p;
      }
      float tc[IDN];
#pragma unroll
      for (int id = 0; id < IDN; ++id) {
        const float den = pd[id] + dpp_swap1(pd[id]);
        tc[id] = xn[id] * __builtin_amdgcn_rcpf(den + EPS);
      }
      float hacc[ODH];
#pragma unroll
      for (int k = 0; k < ODH; ++k) hacc[k] = wr[0][k] * tc[0];
#pragma unroll
      for (int id = 1; id < IDN; ++id)
#pragma unroll
        for (int k = 0; k < ODH; ++k) hacc[k] = fmaf(wr[id][k], tc[id], hacc[k]);
#pragma unroll
      for (int k = 0; k < ODH; ++k) h[k] *= hacc[k];
      float ps = 0.f;
#pragma unroll
      for (int k = 0; k < ODH; ++k) ps += h[k];
      const float hs = ps + dpp_swap1(ps);
      const float r = __builtin_amdgcn_rcpf(hs + EPS);
#pragma unroll
      for (int k = 0; k < ODH; ++k) h[k] *= r;
    }
    float ap = 0.f;
#pragma unroll
    for (int id = 0; id < IDN; ++id) {
      float rec = 0.f;
#pragma unroll
      for (int k = 0; k < ODH; ++k) rec = fmaf(h[k], wr[id][k], rec);
      ap = fmaf(rec, xn[id], ap);
    }
    const float af = ap + dpp_swap1(ap);
    float asum = 0.f;
    const int gbase = grp * 20;
#pragma unroll
    for (int k = 0; k < OCN; ++k) asum += __shfl(af, gbase + 2 * k, 64);
    const float an = af * __builtin_amdgcn_rcpf(asum + EPS);
#pragma unroll
    for (int k = 0; k < ODH; ++k) oacc[k] = fmaf(h[k], an, oacc[k]);
  }
  if (valid) {
    const int base = (bb * OCN + oc) * ODN + half * ODH;
#pragma unroll
    for (int k = 0; k < ODH; ++k) atomicAdd(outg + base + k, oacc[k]);
  }
}

// ---------------------------------------------------------------------------
// Reduce: out[j] += sum_{r in my 36 rows} ws[r][j], 288 rows total.
// grid = (5120/256, 8), block 256 -> 160 blocks; 8 atomic contenders/addr.
// ---------------------------------------------------------------------------
#define RSPLIT 8
#define RROWS  (NGRP / RSPLIT)  // 36
__global__ void caps_reduce(const float* __restrict__ ws, float* __restrict__ outg) {
  const int j = blockIdx.x * 256 + threadIdx.x;
  const int r0 = blockIdx.y * RROWS;
  float s = 0.f;
#pragma unroll
  for (int r = 0; r < RROWS; ++r) s += ws[(size_t)(r0 + r) * OUTN + j];
  atomicAdd(outg + j, s);
}

extern "C" void kernel_launch(void* const* d_in, const int* in_sizes, int n_in,
                              void* d_out, int out_size, void* d_ws, size_t ws_size,
                              hipStream_t stream) {
  const float* x = (const float*)d_in[0];
  const float* w = (const float*)d_in[1];
  float* out = (float*)d_out;
  float* ws = (float*)d_ws;

  hipMemsetAsync(out, 0, OUTN * sizeof(float), stream);

  const size_t need = (size_t)NGRP * OUTN * sizeof(float);  // 5.9 MB

  if (ws_size >= need) {
    caps_main<<<NBLK, 64, 0, stream>>>(x, w, ws);
    caps_reduce<<<dim3(OUTN / 256, RSPLIT), 256, 0, stream>>>(ws, out);
  } else {
    caps_main_atomic<<<NBLK, 64, 0, stream>>>(x, w, out);
  }
}